// Round 10
// baseline (200.975 us; speedup 1.0000x reference)
//
#include <hip/hip_runtime.h>
#include <hip/hip_bf16.h>

typedef unsigned short u16;
typedef unsigned int u32;
using bf16x8 = __attribute__((ext_vector_type(8))) short;  // 8 bf16 (4 VGPRs)
using f32x4  = __attribute__((ext_vector_type(4))) float;  // 4 fp32

#define BB 512
#define TT 256
#define CC 192
#define HH 64

__device__ __forceinline__ u16 f2bf(float f) {
    __hip_bfloat16 h = __float2bfloat16(f);   // RNE
    u16 u; __builtin_memcpy(&u, &h, 2); return u;
}

// ================= prep kernels (unchanged) =================

// W_sw: B-fragment-swizzled weights. Frag fid = n3*6+ks (n3 = mat*4 + ntile, ks = K-step).
// lane (quad,l15) element u  =  W[c = ks*32+quad*8+u][h = (n3&3)*16+l15] of matrix n3>>2.
// NOTE: frags 0..47 are exactly {Q,K} x 4 ntiles x 6 ks in order -> the first
// 49,152 B stage linearly into LDS as the WQK table.
__global__ void wprep_kernel(const float* __restrict__ Wq,
                             const float* __restrict__ Wk,
                             const float* __restrict__ Wv,
                             u16* __restrict__ W_sw) {
    int gid  = blockIdx.x * 256 + threadIdx.x;   // 0..4607 (72 frags * 64 lanes)
    int fid  = gid >> 6, lane = gid & 63;
    int n3   = fid / 6,  ks   = fid % 6;
    int l15  = lane & 15, quad = lane >> 4;
    const float* W = (n3 < 4) ? Wq : (n3 < 8) ? Wk : Wv;
    const int h = (n3 & 3) * 16 + l15;
    u16* dst = W_sw + (size_t)gid * 8;
    #pragma unroll
    for (int u = 0; u < 8; ++u) {
        int c = ks * 32 + quad * 8 + u;
        dst[u] = f2bf(W[c * HH + h]);
    }
}

// poskT[h][t], posqT[h][t]
__global__ void pos_kernel(const float* __restrict__ Wk,
                           const float* __restrict__ Wq,
                           const float* __restrict__ pe,
                           float* __restrict__ poskT, float* __restrict__ posqT) {
    int t = blockIdx.x * 4 + (threadIdx.x >> 6);   // grid 64 x 256
    int h = threadIdx.x & 63;
    float ak = 0.f, aq = 0.f;
    for (int c = 0; c < CC; ++c) {
        float p = pe[t * CC + c];             // group-uniform broadcast
        ak += p * Wk[c * HH + h];             // coalesced
        aq += p * Wq[c * HH + h];
    }
    poskT[h * TT + t] = ak;
    posqT[h * TT + t] = aq;
}

// bias in C/D-fragment layout: bias_sw[(i*16+jt)*64 + lane] = float4 over r,
// component r = bias[row t0+quad*4+r][col jt*16+l15]  (only jt<=i written/read)
__global__ void bias_kernel(const float* __restrict__ poskT,
                            const float* __restrict__ posqT,
                            float4* __restrict__ bias_sw) {
    const int i = blockIdx.x >> 4, jt = blockIdx.x & 15;
    if (jt > i) return;
    const int lane = threadIdx.x;
    const int l15 = lane & 15, quad = lane >> 4;
    const int tq = i * 16 + quad * 4;     // query rows tq..tq+3
    const int jc = jt * 16 + l15;         // key col
    float s[4] = {0.f, 0.f, 0.f, 0.f};
    for (int h = 0; h < HH; ++h) {
        float pq = posqT[h * TT + jc];
        #pragma unroll
        for (int r = 0; r < 4; ++r)
            s[r] += poskT[h * TT + tq + r] * pq;
    }
    bias_sw[blockIdx.x * 64 + lane] = make_float4(s[0], s[1], s[2], s[3]);
}

// ================= fused kernel: QKV projection + flash attention ============
// v4: R8 shape (512 threads, 8 waves -> 2/SIMD) + W_Q/W_K STAGED IN LDS.
// Evidence (R9): VGPR=64 -> the 72-VGPR W hoist never happened; every wave
// re-read 18 KB of W from L2 per chunk (1.15 MB/block aggregate), a serial
// ~250-cyc stall per MFMA operand, wave-count-invariant (R8->R9 null).
// Fix: WQK (48 KB = W_sw frags 0..47, already in order) copied to LDS once
// per block; phase-1 inner loop reads W via ds_read_b128 (~60 cyc, hidden).
// W_V = 6 frags = 24 VGPR in registers (fits the real 64-VGPR allocation).
// LDS total 161,280 B <= 160 KiB (full-LDS workgroups HW-proven by AITER/HK).
// Phase 1: 8 chunks x 32 rows, wave (mh=w>>2 -> m-tile, w4=w&3 -> h-tile),
// T14 prefetch, single X buffer, 2 barriers/chunk.
// Phase 2: R8 body verbatim; wave w owns i-tiles {w, 15-w} (SumJ=17/wave).
// P buffer lives in the dead X region.

#define XP 200                           // X pitch (u16); 400 B rows
#define VP 264
#define PP 40
#define P_ELEMS 640                      // 16*40 u16 per wave
// LDS byte map (16B-aligned):
//   [0,      12800)  X stage (32 rows x 400 B)   /  P in phase 2 (8 x 1280 B)
//   [12800,  61952)  WQK table (48 frags x 1024 B: mat{Q,K} x nt x ks)
//   [61952,  94720)  Q frags  (16 tiles x 2 x 1024 B)
//   [94720, 127488)  K frags
//   [127488,161280)  V^T      (64 x VP u16)
#define WQK_OFF 12800
#define Q_OFF   61952
#define K_OFF   94720
#define V_OFF   127488
#define LDS_TOTAL 161280

__global__ __launch_bounds__(512, 1)
void fused_kernel(const float* __restrict__ x,
                  const u16* __restrict__ W_sw,
                  const float4* __restrict__ bias_sw,
                  float* __restrict__ out) {
    extern __shared__ __align__(16) char smem[];
    u16* Qlds = (u16*)(smem + Q_OFF);
    u16* Klds = (u16*)(smem + K_OFF);
    u16* Vt   = (u16*)(smem + V_OFF);

    const int tid  = threadIdx.x;
    const int w    = tid >> 6;           // 0..7
    const int w4   = w & 3;              // h-tile
    const int mh   = w >> 2;             // m-tile within 32-row chunk
    const int lane = tid & 63;
    const int l15  = lane & 15;
    const int quad = lane >> 4;
    const int b    = blockIdx.x;

    // ---- stage WQK (48 KB) into LDS: 512 thr x 6 x 16 B, linear copy ----
    {
        const uint4* src = (const uint4*)W_sw;
        uint4* dst = (uint4*)(smem + WQK_OFF);
        #pragma unroll
        for (int it = 0; it < 6; ++it)
            dst[it * 512 + tid] = src[it * 512 + tid];
    }

    // ---- W_V fragments (6 = 24 VGPR) in registers ----
    const bf16x8* Wv8 = (const bf16x8*)W_sw;
    bf16x8 WfV[6];
    #pragma unroll
    for (int ks = 0; ks < 6; ++ks)
        WfV[ks] = Wv8[(((8 + w4) * 6) + ks) * 64 + lane];   // mat=2 (V)
    #pragma unroll
    for (int j = 0; j < 6; ++j)
        asm volatile("" : "+v"(WfV[j]));

    // ================= phase 1: projection (8 chunks x 32 rows) =============
    const int hs    = w4 >> 1;
    const int quadp = (w4 * 2 + (l15 >> 3)) & 3;
    const int uu    = l15 & 7;

    // prologue: stage chunk 0
    {
        const float* xb = x + (size_t)b * TT * CC;
        float4 vv[3];
        #pragma unroll
        for (int it = 0; it < 3; ++it)
            vv[it] = *(const float4*)(xb + (it * 512 + tid) * 4);
        u16* xs = (u16*)smem;
        #pragma unroll
        for (int it = 0; it < 3; ++it) {
            const int flat = (it * 512 + tid) * 4;        // 0..6143
            const int row = flat / CC, col = flat % CC;   // CC%4==0: no row cross
            uint2 pk;
            pk.x = (u32)f2bf(vv[it].x) | ((u32)f2bf(vv[it].y) << 16);
            pk.y = (u32)f2bf(vv[it].z) | ((u32)f2bf(vv[it].w) << 16);
            *(uint2*)&xs[row * XP + col] = pk;
        }
    }
    __syncthreads();   // X chunk 0 + WQK table visible

    #pragma unroll 1
    for (int c8 = 0; c8 < 8; ++c8) {
        const bool hn = (c8 < 7);
        // ---- issue next chunk's global loads FIRST (hide under MFMAs) ----
        float4 vnext[3];
        if (hn) {
            const float* xb = x + ((size_t)b * TT + (c8 + 1) * 32) * CC;
            #pragma unroll
            for (int it = 0; it < 3; ++it)
                vnext[it] = *(const float4*)(xb + (it * 512 + tid) * 4);
        }
        // ---- compute: all operands from LDS / registers ----
        const u16* xs = (const u16*)smem;
        f32x4 acc[3];
        #pragma unroll
        for (int i = 0; i < 3; ++i) acc[i] = {0.f, 0.f, 0.f, 0.f};
        #pragma unroll
        for (int ks = 0; ks < 6; ++ks) {
            const bf16x8 a  = *(const bf16x8*)&xs[(mh * 16 + l15) * XP + ks * 32 + quad * 8];
            const bf16x8 wq = *(const bf16x8*)(smem + WQK_OFF + ((w4 * 6 + ks) * 64 + lane) * 16);
            const bf16x8 wk = *(const bf16x8*)(smem + WQK_OFF + (((4 + w4) * 6 + ks) * 64 + lane) * 16);
            acc[0] = __builtin_amdgcn_mfma_f32_16x16x32_bf16(a, wq, acc[0], 0, 0, 0);
            acc[1] = __builtin_amdgcn_mfma_f32_16x16x32_bf16(a, wk, acc[1], 0, 0, 0);
            acc[2] = __builtin_amdgcn_mfma_f32_16x16x32_bf16(a, WfV[ks], acc[2], 0, 0, 0);
        }
        // ---- epilogue: Q/K frags + V^T into LDS ----
        {
            const int i_loc = c8 * 2 + mh;                 // t-tile 0..15
            const int base  = (i_loc * 2 + hs) * 512 + (quadp * 16 + quad * 4) * 8 + uu;
            #pragma unroll
            for (int r = 0; r < 4; ++r) {
                Qlds[base + r * 8] = f2bf(acc[0][r]);      // A-frag layout
                Klds[base + r * 8] = f2bf(acc[1][r]);      // B-frag layout
            }
            #pragma unroll
            for (int r = 0; r < 4; ++r)
                Vt[(w4 * 16 + l15) * VP + i_loc * 16 + quad * 4 + r]
                    = f2bf(acc[2][r]);                     // V^T[h][t]
        }
        __syncthreads();   // xs readers done; epilogue visible (last iter:
                           // doubles as the proj->attn barrier)
        if (hn) {
            u16* xsn = (u16*)smem;
            #pragma unroll
            for (int it = 0; it < 3; ++it) {
                const int flat = (it * 512 + tid) * 4;
                const int row = flat / CC, col = flat % CC;
                uint2 pk;
                pk.x = (u32)f2bf(vnext[it].x) | ((u32)f2bf(vnext[it].y) << 16);
                pk.y = (u32)f2bf(vnext[it].z) | ((u32)f2bf(vnext[it].w) << 16);
                *(uint2*)&xsn[row * XP + col] = pk;
            }
            __syncthreads();   // next chunk staged
        }
    }

    // ================= phase 2: attention =================
    u16* Pw = (u16*)smem + w * P_ELEMS;         // X region is dead now (10.2 KB)
    const float scale = 0.07216878364870322f;  // 192^-0.5
    const f32x4 zero4 = {0.f, 0.f, 0.f, 0.f};
    const bf16x8* qv = (const bf16x8*)Qlds;
    const bf16x8* kv = (const bf16x8*)Klds;

    #pragma unroll 1
    for (int mt = 0; mt < 2; ++mt) {
        // balanced causal sets: wave w owns {w, 15-w}; SumJ = 17 per wave
        const int i  = mt ? 15 - w : w;
        const int t0 = 16 * i;
        const int J  = i + 1;
        const int Pq = (J + 1) >> 1;

        const bf16x8 qf0 = qv[(i * 2 + 0) * 64 + lane];
        const bf16x8 qf1 = qv[(i * 2 + 1) * 64 + lane];

        f32x4 o[4];
        float m4[4], l4[4];
        #pragma unroll
        for (int n = 0; n < 4; ++n) o[n] = zero4;
        #pragma unroll
        for (int r = 0; r < 4; ++r) { m4[r] = -1e30f; l4[r] = 0.f; }

        #pragma unroll
        for (int p = 0; p < 8; ++p) {
            if (p < Pq) {
                const int jt0 = 2 * p, jt1 = 2 * p + 1;
                // ---- S tiles (pair) ----
                f32x4 sa = zero4, sb;
                {
                    bf16x8 k0 = kv[(jt0 * 2 + 0) * 64 + lane];
                    bf16x8 k1 = kv[(jt0 * 2 + 1) * 64 + lane];
                    sa = __builtin_amdgcn_mfma_f32_16x16x32_bf16(qf0, k0, sa, 0, 0, 0);
                    sa = __builtin_amdgcn_mfma_f32_16x16x32_bf16(qf1, k1, sa, 0, 0, 0);
                    const float4 b4 = bias_sw[(i * 16 + jt0) * 64 + lane];
                    sa[0] = sa[0] * scale + b4.x;
                    sa[1] = sa[1] * scale + b4.y;
                    sa[2] = sa[2] * scale + b4.z;
                    sa[3] = sa[3] * scale + b4.w;
                    if (jt0 == i) {
                        #pragma unroll
                        for (int r = 0; r < 4; ++r)
                            if (l15 > quad * 4 + r) sa[r] = -1e30f;
                    }
                }
                if (jt1 < J) {
                    sb = zero4;
                    bf16x8 k0 = kv[(jt1 * 2 + 0) * 64 + lane];
                    bf16x8 k1 = kv[(jt1 * 2 + 1) * 64 + lane];
                    sb = __builtin_amdgcn_mfma_f32_16x16x32_bf16(qf0, k0, sb, 0, 0, 0);
                    sb = __builtin_amdgcn_mfma_f32_16x16x32_bf16(qf1, k1, sb, 0, 0, 0);
                    const float4 b4 = bias_sw[(i * 16 + jt1) * 64 + lane];
                    sb[0] = sb[0] * scale + b4.x;
                    sb[1] = sb[1] * scale + b4.y;
                    sb[2] = sb[2] * scale + b4.z;
                    sb[3] = sb[3] * scale + b4.w;
                    if (jt1 == i) {
                        #pragma unroll
                        for (int r = 0; r < 4; ++r)
                            if (l15 > quad * 4 + r) sb[r] = -1e30f;
                    }
                } else {
                    sb[0] = -1e30f; sb[1] = -1e30f; sb[2] = -1e30f; sb[3] = -1e30f;
                }
                // ---- pair row max (16-lane group shares rows) ----
                float t4[4];
                #pragma unroll
                for (int r = 0; r < 4; ++r) t4[r] = fmaxf(sa[r], sb[r]);
                #pragma unroll
                for (int d = 1; d < 16; d <<= 1) {
                    #pragma unroll
                    for (int r = 0; r < 4; ++r) t4[r] = fmaxf(t4[r], __shfl_xor(t4[r], d, 64));
                }
                // ---- online rescale ----
                float al[4];
                #pragma unroll
                for (int r = 0; r < 4; ++r) {
                    float mn = fmaxf(m4[r], t4[r]);
                    al[r] = __expf(m4[r] - mn);   // first pair: exp(-huge)=0
                    m4[r] = mn;
                    l4[r] *= al[r];
                }
                #pragma unroll
                for (int n = 0; n < 4; ++n)
                #pragma unroll
                for (int r = 0; r < 4; ++r) o[n][r] *= al[r];
                // ---- exp + P -> per-wave LDS ----
                #pragma unroll
                for (int r = 0; r < 4; ++r) {
                    float e0 = __expf(sa[r] - m4[r]);
                    float e1 = __expf(sb[r] - m4[r]);   // invalid tile -> 0
                    l4[r] += e0 + e1;
                    Pw[(quad * 4 + r) * PP + l15]      = f2bf(e0);
                    Pw[(quad * 4 + r) * PP + 16 + l15] = f2bf(e1);
                }
                // ---- PV ----
                bf16x8 pa = *(const bf16x8*)&Pw[l15 * PP + quad * 8];
                #pragma unroll
                for (int n = 0; n < 4; ++n) {
                    bf16x8 bv = *(const bf16x8*)&Vt[(n * 16 + l15) * VP + p * 32 + quad * 8];
                    o[n] = __builtin_amdgcn_mfma_f32_16x16x32_bf16(pa, bv, o[n], 0, 0, 0);
                }
            }
        }
        // ---- row-sum reduce + normalize + store ----
        #pragma unroll
        for (int d = 1; d < 16; d <<= 1) {
            #pragma unroll
            for (int r = 0; r < 4; ++r) l4[r] += __shfl_xor(l4[r], d, 64);
        }
        float rl4[4];
        #pragma unroll
        for (int r = 0; r < 4; ++r) rl4[r] = 1.f / l4[r];
        float* ob = out + ((size_t)b * TT + t0) * HH;
        #pragma unroll
        for (int n = 0; n < 4; ++n)
        #pragma unroll
        for (int r = 0; r < 4; ++r)
            ob[(quad * 4 + r) * HH + n * 16 + l15] = o[n][r] * rl4[r];
    }
}

extern "C" void kernel_launch(void* const* d_in, const int* in_sizes, int n_in,
                              void* d_out, int out_size, void* d_ws, size_t ws_size,
                              hipStream_t stream) {
    const float* x  = (const float*)d_in[0];
    const float* Wk = (const float*)d_in[1];
    const float* Wq = (const float*)d_in[2];
    const float* Wv = (const float*)d_in[3];
    const float* pe = (const float*)d_in[4];
    float* out = (float*)d_out;

    // ws: poskT[16384]f | posqT[16384]f | bias_sw[16384]float4-elems | W_sw[36864]u16
    float*  poskT  = (float*)d_ws;
    float*  posqT  = poskT + TT * HH;
    float4* biassw = (float4*)(posqT + TT * HH);
    u16*    W_sw   = (u16*)((float*)biassw + TT * TT);

    // one-time opt-in for >64K dynamic LDS (host-side, proven R7-R9)
    static bool attr_set = false;
    if (!attr_set) {
        hipFuncSetAttribute(reinterpret_cast<const void*>(fused_kernel),
                            hipFuncAttributeMaxDynamicSharedMemorySize, LDS_TOTAL);
        attr_set = true;
    }

    wprep_kernel<<<18, 256, 0, stream>>>(Wq, Wk, Wv, W_sw);
    pos_kernel<<<TT / 4, 256, 0, stream>>>(Wk, Wq, pe, poskT, posqT);
    bias_kernel<<<256, 64, 0, stream>>>(poskT, posqT, biassw);
    fused_kernel<<<BB, 512, LDS_TOTAL, stream>>>(x, W_sw, biassw, out);
}

// Round 11
// 197.601 us; speedup vs baseline: 1.0171x; 1.0171x over previous
//
#include <hip/hip_runtime.h>
#include <hip/hip_bf16.h>

typedef unsigned short u16;
typedef unsigned int u32;
using bf16x8 = __attribute__((ext_vector_type(8))) short;  // 8 bf16 (4 VGPRs)
using f32x4  = __attribute__((ext_vector_type(4))) float;  // 4 fp32

#define BB 512
#define TT 256
#define CC 192
#define HH 64

__device__ __forceinline__ u16 f2bf(float f) {
    __hip_bfloat16 h = __float2bfloat16(f);   // RNE
    u16 u; __builtin_memcpy(&u, &h, 2); return u;
}

// DPP cross-lane xor-1 / xor-2 within quads: VALU ops, off the LDS pipe
// (replaces ds_bpermute-based __shfl_xor for d=1,2).
__device__ __forceinline__ float dpp_x1(float x) {
    int y = __builtin_amdgcn_update_dpp(0, __float_as_int(x), 0xB1, 0xF, 0xF, true); // quad_perm [1,0,3,2]
    return __int_as_float(y);
}
__device__ __forceinline__ float dpp_x2(float x) {
    int y = __builtin_amdgcn_update_dpp(0, __float_as_int(x), 0x4E, 0xF, 0xF, true); // quad_perm [2,3,0,1]
    return __int_as_float(y);
}

// ================= prep kernels =================
// prep_a: wprep (blocks 0..17) + pos (blocks 18..81) merged into one launch.

__global__ void prep_a(const float* __restrict__ Wq,
                       const float* __restrict__ Wk,
                       const float* __restrict__ Wv,
                       const float* __restrict__ pe,
                       u16* __restrict__ W_sw,
                       float* __restrict__ poskT, float* __restrict__ posqT) {
    if (blockIdx.x < 18) {
        // ---- wprep: W_sw B-fragment swizzle ----
        int gid  = blockIdx.x * 256 + threadIdx.x;   // 0..4607
        int fid  = gid >> 6, lane = gid & 63;
        int n3   = fid / 6,  ks   = fid % 6;
        int l15  = lane & 15, quad = lane >> 4;
        const float* W = (n3 < 4) ? Wq : (n3 < 8) ? Wk : Wv;
        const int h = (n3 & 3) * 16 + l15;
        u16* dst = W_sw + (size_t)gid * 8;
        #pragma unroll
        for (int u = 0; u < 8; ++u) {
            int c = ks * 32 + quad * 8 + u;
            dst[u] = f2bf(W[c * HH + h]);
        }
    } else {
        // ---- pos: poskT[h][t], posqT[h][t] ----
        int bid = blockIdx.x - 18;
        int t = bid * 4 + (threadIdx.x >> 6);
        int h = threadIdx.x & 63;
        float ak = 0.f, aq = 0.f;
        for (int c = 0; c < CC; ++c) {
            float p = pe[t * CC + c];
            ak += p * Wk[c * HH + h];
            aq += p * Wq[c * HH + h];
        }
        poskT[h * TT + t] = ak;
        posqT[h * TT + t] = aq;
    }
}

// bias in C/D-fragment layout (unchanged)
__global__ void bias_kernel(const float* __restrict__ poskT,
                            const float* __restrict__ posqT,
                            float4* __restrict__ bias_sw) {
    const int i = blockIdx.x >> 4, jt = blockIdx.x & 15;
    if (jt > i) return;
    const int lane = threadIdx.x;
    const int l15 = lane & 15, quad = lane >> 4;
    const int tq = i * 16 + quad * 4;
    const int jc = jt * 16 + l15;
    float s[4] = {0.f, 0.f, 0.f, 0.f};
    for (int h = 0; h < HH; ++h) {
        float pq = posqT[h * TT + jc];
        #pragma unroll
        for (int r = 0; r < 4; ++r)
            s[r] += poskT[h * TT + tq + r] * pq;
    }
    bias_sw[blockIdx.x * 64 + lane] = make_float4(s[0], s[1], s[2], s[3]);
}

// ================= fused kernel: QKV projection + flash attention ============
// v5 = R10 + phase-2/LDS diet:
//  - T2 XOR swizzle (byte ^ (row&7)<<4) on BOTH 8-way-conflicted paths:
//    X-stage reads (phase 1) and V^T reads (PV). Writes apply the same XOR;
//    V^T write packed as one b64 (was 4 scalar b16).
//  - DPP quad_perm for xor-1/xor-2 reduce steps: 16 -> 8 bpermutes per pair.
//  - Pair loop ROLLED (for p<Pq, unroll 1): ~8x less phase-2 code (I$ probe).
//  - bias loads hoisted to iteration top (L2 latency overlaps ds_read+MFMA).
// Everything else identical to R10 (512 thr, WQK in LDS, WfV pinned, 161KB).

#define XP 200                           // X pitch (u16); 400 B rows
#define VP 264                           // V^T pitch (u16); 528 B rows
#define PP 40
#define P_ELEMS 640                      // 16*40 u16 per wave
#define WQK_OFF 12800
#define Q_OFF   61952
#define K_OFF   94720
#define V_OFF   127488
#define LDS_TOTAL 161280

__global__ __launch_bounds__(512, 1)
void fused_kernel(const float* __restrict__ x,
                  const u16* __restrict__ W_sw,
                  const float4* __restrict__ bias_sw,
                  float* __restrict__ out) {
    extern __shared__ __align__(16) char smem[];
    u16* Qlds = (u16*)(smem + Q_OFF);
    u16* Klds = (u16*)(smem + K_OFF);
    char* VtB = smem + V_OFF;            // byte-addressed (swizzled)

    const int tid  = threadIdx.x;
    const int w    = tid >> 6;           // 0..7
    const int w4   = w & 3;              // h-tile
    const int mh   = w >> 2;             // m-tile within 32-row chunk
    const int lane = tid & 63;
    const int l15  = lane & 15;
    const int quad = lane >> 4;
    const int b    = blockIdx.x;
    const int swz  = (l15 & 7) << 4;     // per-lane row-XOR for frag reads

    // ---- stage WQK (48 KB) into LDS: linear copy ----
    {
        const uint4* src = (const uint4*)W_sw;
        uint4* dst = (uint4*)(smem + WQK_OFF);
        #pragma unroll
        for (int it = 0; it < 6; ++it)
            dst[it * 512 + tid] = src[it * 512 + tid];
    }

    // ---- W_V fragments (6 = 24 VGPR) in registers, pinned ----
    const bf16x8* Wv8 = (const bf16x8*)W_sw;
    bf16x8 WfV[6];
    #pragma unroll
    for (int ks = 0; ks < 6; ++ks)
        WfV[ks] = Wv8[(((8 + w4) * 6) + ks) * 64 + lane];
    #pragma unroll
    for (int j = 0; j < 6; ++j)
        asm volatile("" : "+v"(WfV[j]));

    // ================= phase 1: projection (8 chunks x 32 rows) =============
    const int hs    = w4 >> 1;
    const int quadp = (w4 * 2 + (l15 >> 3)) & 3;
    const int uu    = l15 & 7;

    // prologue: stage chunk 0 (XOR-swizzled X rows)
    {
        const float* xb = x + (size_t)b * TT * CC;
        float4 vv[3];
        #pragma unroll
        for (int it = 0; it < 3; ++it)
            vv[it] = *(const float4*)(xb + (it * 512 + tid) * 4);
        #pragma unroll
        for (int it = 0; it < 3; ++it) {
            const int flat = (it * 512 + tid) * 4;        // 0..6143
            const int row = flat / CC, col = flat % CC;   // col%4==0
            uint2 pk;
            pk.x = (u32)f2bf(vv[it].x) | ((u32)f2bf(vv[it].y) << 16);
            pk.y = (u32)f2bf(vv[it].z) | ((u32)f2bf(vv[it].w) << 16);
            *(uint2*)(smem + row * (XP * 2) + ((col * 2) ^ ((row & 7) << 4))) = pk;
        }
    }
    __syncthreads();

    #pragma unroll 1
    for (int c8 = 0; c8 < 8; ++c8) {
        const bool hn = (c8 < 7);
        float4 vnext[3];
        if (hn) {
            const float* xb = x + ((size_t)b * TT + (c8 + 1) * 32) * CC;
            #pragma unroll
            for (int it = 0; it < 3; ++it)
                vnext[it] = *(const float4*)(xb + (it * 512 + tid) * 4);
        }
        // ---- compute: X reads swizzled; WQK from LDS; V from registers ----
        f32x4 acc[3];
        #pragma unroll
        for (int i = 0; i < 3; ++i) acc[i] = {0.f, 0.f, 0.f, 0.f};
        #pragma unroll
        for (int ks = 0; ks < 6; ++ks) {
            const bf16x8 a  = *(const bf16x8*)(smem + (mh * 16 + l15) * (XP * 2)
                                               + ((ks * 64 + quad * 16) ^ swz));
            const bf16x8 wq = *(const bf16x8*)(smem + WQK_OFF + ((w4 * 6 + ks) * 64 + lane) * 16);
            const bf16x8 wk = *(const bf16x8*)(smem + WQK_OFF + (((4 + w4) * 6 + ks) * 64 + lane) * 16);
            acc[0] = __builtin_amdgcn_mfma_f32_16x16x32_bf16(a, wq, acc[0], 0, 0, 0);
            acc[1] = __builtin_amdgcn_mfma_f32_16x16x32_bf16(a, wk, acc[1], 0, 0, 0);
            acc[2] = __builtin_amdgcn_mfma_f32_16x16x32_bf16(a, WfV[ks], acc[2], 0, 0, 0);
        }
        // ---- epilogue: Q/K frags + swizzled V^T (packed b64) into LDS ----
        {
            const int i_loc = c8 * 2 + mh;                 // t-tile 0..15
            const int base  = (i_loc * 2 + hs) * 512 + (quadp * 16 + quad * 4) * 8 + uu;
            #pragma unroll
            for (int r = 0; r < 4; ++r) {
                Qlds[base + r * 8] = f2bf(acc[0][r]);      // A-frag layout
                Klds[base + r * 8] = f2bf(acc[1][r]);      // B-frag layout
            }
            // V^T row = w4*16+l15 (row&7 == l15&7), cols i_loc*16+quad*4+..+3
            uint2 pv;
            pv.x = (u32)f2bf(acc[2][0]) | ((u32)f2bf(acc[2][1]) << 16);
            pv.y = (u32)f2bf(acc[2][2]) | ((u32)f2bf(acc[2][3]) << 16);
            *(uint2*)(VtB + (w4 * 16 + l15) * (VP * 2)
                      + ((i_loc * 32 + quad * 8) ^ swz)) = pv;
        }
        __syncthreads();
        if (hn) {
            #pragma unroll
            for (int it = 0; it < 3; ++it) {
                const int flat = (it * 512 + tid) * 4;
                const int row = flat / CC, col = flat % CC;
                uint2 pk;
                pk.x = (u32)f2bf(vnext[it].x) | ((u32)f2bf(vnext[it].y) << 16);
                pk.y = (u32)f2bf(vnext[it].z) | ((u32)f2bf(vnext[it].w) << 16);
                *(uint2*)(smem + row * (XP * 2) + ((col * 2) ^ ((row & 7) << 4))) = pk;
            }
            __syncthreads();
        }
    }

    // ================= phase 2: attention =================
    u16* Pw = (u16*)smem + w * P_ELEMS;         // X region is dead now
    const float scale = 0.07216878364870322f;  // 192^-0.5
    const f32x4 zero4 = {0.f, 0.f, 0.f, 0.f};
    const bf16x8* qv = (const bf16x8*)Qlds;
    const bf16x8* kv = (const bf16x8*)Klds;

    #pragma unroll 1
    for (int mt = 0; mt < 2; ++mt) {
        // balanced causal sets: wave w owns {w, 15-w}; SumJ = 17 per wave
        const int i  = mt ? 15 - w : w;
        const int t0 = 16 * i;
        const int J  = i + 1;
        const int Pq = (J + 1) >> 1;

        const bf16x8 qf0 = qv[(i * 2 + 0) * 64 + lane];
        const bf16x8 qf1 = qv[(i * 2 + 1) * 64 + lane];

        f32x4 o[4];
        float m4[4], l4[4];
        #pragma unroll
        for (int n = 0; n < 4; ++n) o[n] = zero4;
        #pragma unroll
        for (int r = 0; r < 4; ++r) { m4[r] = -1e30f; l4[r] = 0.f; }

        #pragma unroll 1
        for (int p = 0; p < Pq; ++p) {
            const int jt0 = 2 * p, jt1 = 2 * p + 1;
            // bias hoisted: L2 latency overlaps the ds_reads + MFMAs below
            const float4 b4a = bias_sw[(i * 16 + jt0) * 64 + lane];
            const float4 b4b = bias_sw[(i * 16 + jt1) * 64 + lane];  // in-bounds; unused if jt1>=J
            // ---- S tiles (pair) ----
            f32x4 sa = zero4, sb;
            {
                bf16x8 k0 = kv[(jt0 * 2 + 0) * 64 + lane];
                bf16x8 k1 = kv[(jt0 * 2 + 1) * 64 + lane];
                sa = __builtin_amdgcn_mfma_f32_16x16x32_bf16(qf0, k0, sa, 0, 0, 0);
                sa = __builtin_amdgcn_mfma_f32_16x16x32_bf16(qf1, k1, sa, 0, 0, 0);
                sa[0] = sa[0] * scale + b4a.x;
                sa[1] = sa[1] * scale + b4a.y;
                sa[2] = sa[2] * scale + b4a.z;
                sa[3] = sa[3] * scale + b4a.w;
                if (jt0 == i) {
                    #pragma unroll
                    for (int r = 0; r < 4; ++r)
                        if (l15 > quad * 4 + r) sa[r] = -1e30f;
                }
            }
            if (jt1 < J) {
                sb = zero4;
                bf16x8 k0 = kv[(jt1 * 2 + 0) * 64 + lane];
                bf16x8 k1 = kv[(jt1 * 2 + 1) * 64 + lane];
                sb = __builtin_amdgcn_mfma_f32_16x16x32_bf16(qf0, k0, sb, 0, 0, 0);
                sb = __builtin_amdgcn_mfma_f32_16x16x32_bf16(qf1, k1, sb, 0, 0, 0);
                sb[0] = sb[0] * scale + b4b.x;
                sb[1] = sb[1] * scale + b4b.y;
                sb[2] = sb[2] * scale + b4b.z;
                sb[3] = sb[3] * scale + b4b.w;
                if (jt1 == i) {
                    #pragma unroll
                    for (int r = 0; r < 4; ++r)
                        if (l15 > quad * 4 + r) sb[r] = -1e30f;
                }
            } else {
                sb[0] = -1e30f; sb[1] = -1e30f; sb[2] = -1e30f; sb[3] = -1e30f;
            }
            // ---- pair row max over 16-lane group: DPP (d=1,2) + shfl (d=4,8) ----
            float t4[4];
            #pragma unroll
            for (int r = 0; r < 4; ++r) t4[r] = fmaxf(sa[r], sb[r]);
            #pragma unroll
            for (int r = 0; r < 4; ++r) {
                t4[r] = fmaxf(t4[r], dpp_x1(t4[r]));
                t4[r] = fmaxf(t4[r], dpp_x2(t4[r]));
                t4[r] = fmaxf(t4[r], __shfl_xor(t4[r], 4, 64));
                t4[r] = fmaxf(t4[r], __shfl_xor(t4[r], 8, 64));
            }
            // ---- online rescale ----
            float al[4];
            #pragma unroll
            for (int r = 0; r < 4; ++r) {
                float mn = fmaxf(m4[r], t4[r]);
                al[r] = __expf(m4[r] - mn);
                m4[r] = mn;
                l4[r] *= al[r];
            }
            #pragma unroll
            for (int n = 0; n < 4; ++n)
            #pragma unroll
            for (int r = 0; r < 4; ++r) o[n][r] *= al[r];
            // ---- exp + P -> per-wave LDS ----
            #pragma unroll
            for (int r = 0; r < 4; ++r) {
                float e0 = __expf(sa[r] - m4[r]);
                float e1 = __expf(sb[r] - m4[r]);
                l4[r] += e0 + e1;
                Pw[(quad * 4 + r) * PP + l15]      = f2bf(e0);
                Pw[(quad * 4 + r) * PP + 16 + l15] = f2bf(e1);
            }
            // ---- PV (swizzled V^T reads: ~2-way banks, was 8-way) ----
            bf16x8 pa = *(const bf16x8*)&Pw[l15 * PP + quad * 8];
            #pragma unroll
            for (int n = 0; n < 4; ++n) {
                bf16x8 bv = *(const bf16x8*)(VtB + (n * 16 + l15) * (VP * 2)
                                             + ((p * 64 + quad * 16) ^ swz));
                o[n] = __builtin_amdgcn_mfma_f32_16x16x32_bf16(pa, bv, o[n], 0, 0, 0);
            }
        }
        // ---- row-sum reduce (DPP+shfl) + normalize + store ----
        #pragma unroll
        for (int r = 0; r < 4; ++r) {
            l4[r] += dpp_x1(l4[r]);
            l4[r] += dpp_x2(l4[r]);
            l4[r] += __shfl_xor(l4[r], 4, 64);
            l4[r] += __shfl_xor(l4[r], 8, 64);
        }
        float rl4[4];
        #pragma unroll
        for (int r = 0; r < 4; ++r) rl4[r] = 1.f / l4[r];
        float* ob = out + ((size_t)b * TT + t0) * HH;
        #pragma unroll
        for (int n = 0; n < 4; ++n)
        #pragma unroll
        for (int r = 0; r < 4; ++r)
            ob[(quad * 4 + r) * HH + n * 16 + l15] = o[n][r] * rl4[r];
    }
}

extern "C" void kernel_launch(void* const* d_in, const int* in_sizes, int n_in,
                              void* d_out, int out_size, void* d_ws, size_t ws_size,
                              hipStream_t stream) {
    const float* x  = (const float*)d_in[0];
    const float* Wk = (const float*)d_in[1];
    const float* Wq = (const float*)d_in[2];
    const float* Wv = (const float*)d_in[3];
    const float* pe = (const float*)d_in[4];
    float* out = (float*)d_out;

    // ws: poskT[16384]f | posqT[16384]f | bias_sw[16384]float4-elems | W_sw[36864]u16
    float*  poskT  = (float*)d_ws;
    float*  posqT  = poskT + TT * HH;
    float4* biassw = (float4*)(posqT + TT * HH);
    u16*    W_sw   = (u16*)((float*)biassw + TT * TT);

    static bool attr_set = false;
    if (!attr_set) {
        hipFuncSetAttribute(reinterpret_cast<const void*>(fused_kernel),
                            hipFuncAttributeMaxDynamicSharedMemorySize, LDS_TOTAL);
        attr_set = true;
    }

    prep_a<<<18 + TT / 4, 256, 0, stream>>>(Wq, Wk, Wv, pe, W_sw, poskT, posqT);
    bias_kernel<<<256, 64, 0, stream>>>(poskT, posqT, biassw);
    fused_kernel<<<BB, 512, LDS_TOTAL, stream>>>(x, W_sw, biassw, out);
}